// Round 3
// baseline (125.288 us; speedup 1.0000x reference)
//
#include <hip/hip_runtime.h>
#include <hip/hip_bf16.h>

typedef __bf16 bf16x8 __attribute__((ext_vector_type(8)));
typedef unsigned short u16x8 __attribute__((ext_vector_type(8)));
typedef unsigned int u32x4 __attribute__((ext_vector_type(4)));
typedef float f32x4 __attribute__((ext_vector_type(4)));

#define SLEN 2048
#define DDIM 128
#define NH   32
#define NKVH 8
#define QBLK 64
#define KVB  32
#define KPAD 136   // u16: 272B row, 16B aligned, slot-spread
#define VPAD 40    // u16: 80B row, 16B aligned, slot-spread
#define PW   20    // u32 per P row: 80B, 16B aligned

static __device__ __forceinline__ unsigned cvt_pk_bf16(float lo, float hi) {
  unsigned r;
  asm("v_cvt_pk_bf16_f32 %0, %1, %2" : "=v"(r) : "v"(lo), "v"(hi));
  return r;  // lo -> D[15:0], hi -> D[31:16]
}

static __device__ __forceinline__ f32x4 mfma_bf16(u16x8 a, u16x8 b, f32x4 c) {
  return __builtin_amdgcn_mfma_f32_16x16x32_bf16(
      __builtin_bit_cast(bf16x8, a), __builtin_bit_cast(bf16x8, b), c, 0, 0, 0);
}

// ---- prepass: K fp32 -> bf16 ----
__global__ __launch_bounds__(256) void conv_k(const float* __restrict__ src,
                                              unsigned* __restrict__ dst) {
  const int i = blockIdx.x * 256 + threadIdx.x;
  const float4 f0 = ((const float4*)src)[2 * i];
  const float4 f1 = ((const float4*)src)[2 * i + 1];
  u32x4 o = { cvt_pk_bf16(f0.x, f0.y), cvt_pk_bf16(f0.z, f0.w),
              cvt_pk_bf16(f1.x, f1.y), cvt_pk_bf16(f1.z, f1.w) };
  ((u32x4*)dst)[i] = o;
}

// ---- prepass: V fp32 [kvh][s][d] -> bf16 transposed [kvh][d][s] ----
__global__ __launch_bounds__(256) void conv_vt(const float* __restrict__ v,
                                               unsigned short* __restrict__ vt) {
  __shared__ unsigned T32[32][17];  // [s_local][d_pair]
  const int b   = blockIdx.x;       // kvh*256 + st*4 + dt
  const int dt  = b & 3;
  const int st  = (b >> 2) & 63;
  const int kvh = b >> 8;
  const int r  = threadIdx.x >> 3;  // s_local
  const int cg = threadIdx.x & 7;   // d chunk of 4
  const float4 f = *(const float4*)(v + ((size_t)(kvh * SLEN + st * 32 + r) * DDIM) + dt * 32 + cg * 4);
  T32[r][cg * 2]     = cvt_pk_bf16(f.x, f.y);
  T32[r][cg * 2 + 1] = cvt_pk_bf16(f.z, f.w);
  __syncthreads();
  const int dr = threadIdx.x >> 3;  // d_local
  const unsigned sel = (dr & 1) ? 0x07060302u : 0x05040100u;
  const unsigned a0 = T32[cg * 4 + 0][dr >> 1], a1 = T32[cg * 4 + 1][dr >> 1];
  const unsigned a2 = T32[cg * 4 + 2][dr >> 1], a3 = T32[cg * 4 + 3][dr >> 1];
  uint2 o;
  o.x = __builtin_amdgcn_perm(a1, a0, sel);  // {s0,s1} at d=dr
  o.y = __builtin_amdgcn_perm(a3, a2, sel);  // {s2,s3}
  *(uint2*)(vt + (size_t)kvh * DDIM * SLEN + (size_t)(dt * 32 + dr) * SLEN + st * 32 + cg * 4) = o;
}

__global__ __launch_bounds__(256, 4) void attn_fwd(
    const float* __restrict__ q, const unsigned short* __restrict__ kbf,
    const unsigned short* __restrict__ vtg, const float* __restrict__ sinks,
    const int* __restrict__ bwp, float* __restrict__ out) {
  __shared__ unsigned short Kl[KVB][KPAD];   // K tile row-major bf16
  __shared__ unsigned short Vt[DDIM][VPAD];  // V tile transposed
  __shared__ unsigned Pl[4][16][PW];         // P packed: u32 = (P[q][ln], P[q][16+ln])

  const int tid  = threadIdx.x;
  const int wid  = tid >> 6;
  const int lane = tid & 63;
  const int ln   = lane & 15;
  const int hi   = lane >> 4;

  // XCD swizzle: launched id B -> logical L so that kvh == B&7 (one kvh per XCD)
  const int B = blockIdx.x;
  const int L = (B & 7) * 128 + (B >> 3);
  const int h   = L >> 5;
  const int qt  = L & 31;
  const int q0  = qt * QBLK;
  const int kvh = h >> 2;            // GQA ratio 4
  const int qrow0 = q0 + wid * 16;

  const int bwv    = bwp[0];
  const int lo_off = (bwv > 0) ? (bwv - 1) : SLEN;
  const int klo    = max(0, q0 - lo_off);
  const int khi    = q0 + QBLK - 1;

  const float sm_scale = 0.08838834764831845f;  // 1/sqrt(128)

  // ---- Q fragments ----
  u16x8 qf[4];
  {
    const float* qp = q + ((size_t)(h * SLEN + qrow0 + ln) * DDIM) + hi * 8;
    #pragma unroll
    for (int dk = 0; dk < 4; ++dk) {
      float4 f0 = *(const float4*)(qp + dk * 32);
      float4 f1 = *(const float4*)(qp + dk * 32 + 4);
      u32x4 t = { cvt_pk_bf16(f0.x, f0.y), cvt_pk_bf16(f0.z, f0.w),
                  cvt_pk_bf16(f1.x, f1.y), cvt_pk_bf16(f1.z, f1.w) };
      qf[dk] = __builtin_bit_cast(u16x8, t);
    }
  }

  const float sink = sinks[h];
  float m[4], l[4];
  f32x4 oacc[8];
  #pragma unroll
  for (int r = 0; r < 4; ++r) { m[r] = sink; l[r] = 1.0f; }
  #pragma unroll
  for (int nt = 0; nt < 8; ++nt) oacc[nt] = f32x4{0.f, 0.f, 0.f, 0.f};

  const int kb0 = (klo >> 5) << 5;
  const unsigned short* Kg = kbf + (size_t)kvh * SLEN * DDIM;
  const unsigned short* Vg = vtg + (size_t)kvh * DDIM * SLEN;

  // staging coords (2 chunks per thread each for K and V)
  const int kr0 = tid >> 4,          kc0 = (tid & 15) * 8;
  const int kr1 = (256 + tid) >> 4;  // 16 + kr0
  const int vr0 = tid >> 2,          vc0 = (tid & 3) * 8;
  const int vr1 = (256 + tid) >> 2;  // 64 + vr0

  u16x8 pk0, pk1, pv0, pv1;  // prefetch registers
  {
    const int nb = kb0;
    pk0 = *(const u16x8*)(Kg + (size_t)(nb + kr0) * DDIM + kc0);
    pk1 = *(const u16x8*)(Kg + (size_t)(nb + kr1) * DDIM + kc0);
    pv0 = *(const u16x8*)(Vg + (size_t)vr0 * SLEN + nb + vc0);
    pv1 = *(const u16x8*)(Vg + (size_t)vr1 * SLEN + nb + vc0);
  }

  for (int kb = kb0; kb <= khi; kb += KVB) {
    __syncthreads();  // previous tile fully consumed
    *(u16x8*)&Kl[kr0][kc0] = pk0;
    *(u16x8*)&Kl[kr1][kc0] = pk1;
    *(u16x8*)&Vt[vr0][vc0] = pv0;
    *(u16x8*)&Vt[vr1][vc0] = pv1;
    __syncthreads();

    // issue next tile's loads now; consumed at next iteration's ds_write
    {
      const int nb = min(kb + KVB, SLEN - KVB);
      pk0 = *(const u16x8*)(Kg + (size_t)(nb + kr0) * DDIM + kc0);
      pk1 = *(const u16x8*)(Kg + (size_t)(nb + kr1) * DDIM + kc0);
      pv0 = *(const u16x8*)(Vg + (size_t)vr0 * SLEN + nb + vc0);
      pv1 = *(const u16x8*)(Vg + (size_t)vr1 * SLEN + nb + vc0);
    }

    if (kb > qrow0 + 15) continue;                  // above causal diag
    if (kb + KVB - 1 < qrow0 - lo_off) continue;    // before window

    // ---- QK^T: S[16q x 32k] ----
    f32x4 sacc0 = {0,0,0,0}, sacc1 = {0,0,0,0};
    #pragma unroll
    for (int dk = 0; dk < 4; ++dk)
      sacc0 = mfma_bf16(qf[dk], *(const u16x8*)&Kl[ln][dk*32 + hi*8], sacc0);
    #pragma unroll
    for (int dk = 0; dk < 4; ++dk)
      sacc1 = mfma_bf16(qf[dk], *(const u16x8*)&Kl[16 + ln][dk*32 + hi*8], sacc1);

    // ---- online softmax with defer-max (T13, THR=8) ----
    float vv0[4], vv1[4], mx[4];
    bool need = false;
    #pragma unroll
    for (int r = 0; r < 4; ++r) {
      const int qpos = qrow0 + hi*4 + r;
      const int kp0 = kb + ln, kp1 = kb + 16 + ln;
      const bool ok0 = (kp0 <= qpos) && (kp0 >= qpos - lo_off);
      const bool ok1 = (kp1 <= qpos) && (kp1 >= qpos - lo_off);
      vv0[r] = ok0 ? sacc0[r] * sm_scale : -1e30f;
      vv1[r] = ok1 ? sacc1[r] * sm_scale : -1e30f;
      float t = fmaxf(vv0[r], vv1[r]);
      #pragma unroll
      for (int off = 1; off < 16; off <<= 1)
        t = fmaxf(t, __shfl_xor(t, off));
      mx[r] = t;
      need = need || (t > m[r] + 8.0f);
    }
    if (__any(need)) {
      #pragma unroll
      for (int r = 0; r < 4; ++r) {
        const float mn   = fmaxf(m[r], mx[r]);
        const float corr = __expf(m[r] - mn);
        l[r] *= corr;
        m[r] = mn;
        #pragma unroll
        for (int nt = 0; nt < 8; ++nt) oacc[nt][r] *= corr;
      }
    }
    #pragma unroll
    for (int r = 0; r < 4; ++r) {
      const float p0 = __expf(vv0[r] - m[r]);
      const float p1 = __expf(vv1[r] - m[r]);
      float ps = p0 + p1;
      #pragma unroll
      for (int off = 1; off < 16; off <<= 1)
        ps += __shfl_xor(ps, off);
      l[r] += ps;
      Pl[wid][hi*4 + r][ln] = cvt_pk_bf16(p0, p1);  // one b32 store
    }

    // ---- PV: O += P[16x32] * V[32x128] ----
    // rebuild A-frag: lane (ln,hi) needs P[q=ln][k=hi*8..hi*8+7]
    u16x8 pa;
    {
      const unsigned* pr = &Pl[wid][ln][(hi & 1) * 8];
      u32x4 wa = *(const u32x4*)pr;
      u32x4 wb = *(const u32x4*)(pr + 4);
      const unsigned sel = (hi < 2) ? 0x05040100u : 0x07060302u;
      u32x4 t = { __builtin_amdgcn_perm(wa[1], wa[0], sel),
                  __builtin_amdgcn_perm(wa[3], wa[2], sel),
                  __builtin_amdgcn_perm(wb[1], wb[0], sel),
                  __builtin_amdgcn_perm(wb[3], wb[2], sel) };
      pa = __builtin_bit_cast(u16x8, t);
    }
    #pragma unroll
    for (int nt = 0; nt < 8; ++nt) {
      const u16x8 vb = *(const u16x8*)&Vt[nt*16 + ln][hi*8];
      oacc[nt] = mfma_bf16(pa, vb, oacc[nt]);
    }
  }

  // ---- epilogue: out = O / l ----
  #pragma unroll
  for (int r = 0; r < 4; ++r) {
    const float rl = 1.0f / l[r];
    const int qpos = qrow0 + hi*4 + r;
    float* op = out + ((size_t)(h * SLEN + qpos) * DDIM) + ln;
    #pragma unroll
    for (int nt = 0; nt < 8; ++nt) op[nt * 16] = oacc[nt][r] * rl;
  }
}

extern "C" void kernel_launch(void* const* d_in, const int* in_sizes, int n_in,
                              void* d_out, int out_size, void* d_ws, size_t ws_size,
                              hipStream_t stream) {
  const float* q     = (const float*)d_in[0];
  const float* k     = (const float*)d_in[1];
  const float* v     = (const float*)d_in[2];
  const float* sinks = (const float*)d_in[3];
  const int*   bw    = (const int*)d_in[4];
  float* out = (float*)d_out;

  unsigned short* kbf = (unsigned short*)d_ws;                 // 8.39 MB
  unsigned short* vtg = kbf + (size_t)NKVH * SLEN * DDIM;      // 8.39 MB

  conv_k <<<dim3((NKVH*SLEN*DDIM) / (256*8)), 256, 0, stream>>>(k, (unsigned*)kbf);
  conv_vt<<<dim3(NKVH * 64 * 4),              256, 0, stream>>>(v, vtg);
  attn_fwd<<<dim3(NH * (SLEN / QBLK)),        256, 0, stream>>>(q, kbf, vtg, sinks, bw, out);
}

// Round 4
// 111.423 us; speedup vs baseline: 1.1244x; 1.1244x over previous
//
#include <hip/hip_runtime.h>
#include <hip/hip_bf16.h>

typedef __bf16 bf16x8 __attribute__((ext_vector_type(8)));
typedef unsigned short u16x8 __attribute__((ext_vector_type(8)));
typedef unsigned int u32x4 __attribute__((ext_vector_type(4)));
typedef float f32x4 __attribute__((ext_vector_type(4)));

#define SLEN 2048
#define DDIM 128
#define NH   32
#define NKVH 8
#define QBLK 64
#define KVB  32
#define KPAD 136
#define VPAD 40
#define PW   20
#define MINIT  -1e30f
#define MASKED -3e30f

static __device__ __forceinline__ unsigned short f2bfu(float f) {
  union { float f; unsigned u; } x; x.f = f;
  return (unsigned short)((x.u + 0x7fffu + ((x.u >> 16) & 1u)) >> 16);
}
static __device__ __forceinline__ float bfu2f(unsigned short u) {
  union { unsigned u; float f; } x; x.u = ((unsigned)u) << 16;
  return x.f;
}
static __device__ __forceinline__ unsigned cvt_pk_bf16(float lo, float hi) {
  unsigned r;
  asm("v_cvt_pk_bf16_f32 %0, %1, %2" : "=v"(r) : "v"(lo), "v"(hi));
  return r;
}
static __device__ __forceinline__ f32x4 mfma_bf16(u16x8 a, u16x8 b, f32x4 c) {
  return __builtin_amdgcn_mfma_f32_16x16x32_bf16(
      __builtin_bit_cast(bf16x8, a), __builtin_bit_cast(bf16x8, b), c, 0, 0, 0);
}

// ---- prepass: K fp32 -> bf16 ----
__global__ __launch_bounds__(256) void conv_k(const float* __restrict__ src,
                                              unsigned* __restrict__ dst) {
  const int i = blockIdx.x * 256 + threadIdx.x;
  const float4 f0 = ((const float4*)src)[2 * i];
  const float4 f1 = ((const float4*)src)[2 * i + 1];
  u32x4 o = { cvt_pk_bf16(f0.x, f0.y), cvt_pk_bf16(f0.z, f0.w),
              cvt_pk_bf16(f1.x, f1.y), cvt_pk_bf16(f1.z, f1.w) };
  ((u32x4*)dst)[i] = o;
}

// ---- prepass: V fp32 [kvh][s][d] -> bf16 transposed [kvh][d][s] ----
__global__ __launch_bounds__(256) void conv_vt(const float* __restrict__ v,
                                               unsigned short* __restrict__ vt) {
  __shared__ unsigned T32[32][17];
  const int b   = blockIdx.x;
  const int dt  = b & 3;
  const int st  = (b >> 2) & 63;
  const int kvh = b >> 8;
  const int r  = threadIdx.x >> 3;
  const int cg = threadIdx.x & 7;
  const float4 f = *(const float4*)(v + ((size_t)(kvh * SLEN + st * 32 + r) * DDIM) + dt * 32 + cg * 4);
  T32[r][cg * 2]     = cvt_pk_bf16(f.x, f.y);
  T32[r][cg * 2 + 1] = cvt_pk_bf16(f.z, f.w);
  __syncthreads();
  const int dr = threadIdx.x >> 3;
  const unsigned sel = (dr & 1) ? 0x07060302u : 0x05040100u;
  const unsigned a0 = T32[cg * 4 + 0][dr >> 1], a1 = T32[cg * 4 + 1][dr >> 1];
  const unsigned a2 = T32[cg * 4 + 2][dr >> 1], a3 = T32[cg * 4 + 3][dr >> 1];
  uint2 o;
  o.x = __builtin_amdgcn_perm(a1, a0, sel);
  o.y = __builtin_amdgcn_perm(a3, a2, sel);
  *(uint2*)(vt + (size_t)kvh * DDIM * SLEN + (size_t)(dt * 32 + dr) * SLEN + st * 32 + cg * 4) = o;
}

// ---- attention chunk kernel ----
// nch==1: full KV range, finalize with sink, write out.
// nch==2: half KV range per chunk, write raw partial (O bf16, m, l f32) to ws.
__global__ __launch_bounds__(256, 4) void attn_fwd(
    const float* __restrict__ q, const unsigned short* __restrict__ kbf,
    const unsigned short* __restrict__ vtg, const float* __restrict__ sinks,
    const int* __restrict__ bwp, float* __restrict__ out,
    unsigned short* __restrict__ pO, float* __restrict__ pm,
    float* __restrict__ pl, const int nch) {
  __shared__ unsigned short Kl[KVB][KPAD];
  __shared__ unsigned short Vt[DDIM][VPAD];
  __shared__ unsigned Pl[4][16][PW];

  const int tid  = threadIdx.x;
  const int wid  = tid >> 6;
  const int lane = tid & 63;
  const int ln   = lane & 15;
  const int hi   = lane >> 4;

  // B -> (h, qt, c): XCD = B&7 hosts kvh==B&7; qt descending (long chunks first)
  const int B   = blockIdx.x;
  const int x   = B & 7;
  const int j   = B >> 3;           // 0..(128*nch-1)
  const int per = 4 * nch;
  const int qt  = 31 - (j / per);
  const int rem = j % per;
  const int hh  = (nch == 2) ? (rem >> 1) : rem;
  const int c   = (nch == 2) ? (rem & 1) : 0;
  const int h   = x * 4 + hh;
  const int kvh = x;
  const int q0  = qt * QBLK;
  const int qrow0 = q0 + wid * 16;

  const int bwv    = bwp[0];
  const int lo_off = (bwv > 0) ? (bwv - 1) : SLEN;

  // tile range for this chunk
  const int T0 = max(0, q0 - lo_off) >> 5;
  const int T1 = (q0 + QBLK - 1) >> 5;
  const int N  = T1 - T0 + 1;
  const int ch = (N + nch - 1) / nch;
  const int Ts = T0 + c * ch;
  const int Te = min(T1, Ts + ch - 1);

  const float sm_scale = 0.08838834764831845f;

  // ---- Q fragments ----
  u16x8 qf[4];
  {
    const float* qp = q + ((size_t)(h * SLEN + qrow0 + ln) * DDIM) + hi * 8;
    #pragma unroll
    for (int dk = 0; dk < 4; ++dk) {
      float4 f0 = *(const float4*)(qp + dk * 32);
      float4 f1 = *(const float4*)(qp + dk * 32 + 4);
      u32x4 t = { cvt_pk_bf16(f0.x, f0.y), cvt_pk_bf16(f0.z, f0.w),
                  cvt_pk_bf16(f1.x, f1.y), cvt_pk_bf16(f1.z, f1.w) };
      qf[dk] = __builtin_bit_cast(u16x8, t);
    }
  }

  float m[4], l[4];
  f32x4 oacc[8];
  #pragma unroll
  for (int r = 0; r < 4; ++r) { m[r] = MINIT; l[r] = 0.0f; }
  #pragma unroll
  for (int nt = 0; nt < 8; ++nt) oacc[nt] = f32x4{0.f, 0.f, 0.f, 0.f};

  const unsigned short* Kg = kbf + (size_t)kvh * SLEN * DDIM;
  const unsigned short* Vg = vtg + (size_t)kvh * DDIM * SLEN;

  const int kr0 = tid >> 4,          kc0 = (tid & 15) * 8;
  const int kr1 = (256 + tid) >> 4;
  const int vr0 = tid >> 2,          vc0 = (tid & 3) * 8;
  const int vr1 = (256 + tid) >> 2;

  const int kbS = Ts * 32, kbE = Te * 32;

  u16x8 pk0, pk1, pv0, pv1;
  {
    pk0 = *(const u16x8*)(Kg + (size_t)(kbS + kr0) * DDIM + kc0);
    pk1 = *(const u16x8*)(Kg + (size_t)(kbS + kr1) * DDIM + kc0);
    pv0 = *(const u16x8*)(Vg + (size_t)vr0 * SLEN + kbS + vc0);
    pv1 = *(const u16x8*)(Vg + (size_t)vr1 * SLEN + kbS + vc0);
  }

  for (int kb = kbS; kb <= kbE; kb += KVB) {
    __syncthreads();
    *(u16x8*)&Kl[kr0][kc0] = pk0;
    *(u16x8*)&Kl[kr1][kc0] = pk1;
    *(u16x8*)&Vt[vr0][vc0] = pv0;
    *(u16x8*)&Vt[vr1][vc0] = pv1;
    __syncthreads();

    {
      const int nb = min(kb + KVB, kbE);
      pk0 = *(const u16x8*)(Kg + (size_t)(nb + kr0) * DDIM + kc0);
      pk1 = *(const u16x8*)(Kg + (size_t)(nb + kr1) * DDIM + kc0);
      pv0 = *(const u16x8*)(Vg + (size_t)vr0 * SLEN + nb + vc0);
      pv1 = *(const u16x8*)(Vg + (size_t)vr1 * SLEN + nb + vc0);
    }

    if (kb > qrow0 + 15) continue;
    if (kb + KVB - 1 < qrow0 - lo_off) continue;

    // ---- QK^T ----
    f32x4 sacc0 = {0,0,0,0}, sacc1 = {0,0,0,0};
    #pragma unroll
    for (int dk = 0; dk < 4; ++dk)
      sacc0 = mfma_bf16(qf[dk], *(const u16x8*)&Kl[ln][dk*32 + hi*8], sacc0);
    #pragma unroll
    for (int dk = 0; dk < 4; ++dk)
      sacc1 = mfma_bf16(qf[dk], *(const u16x8*)&Kl[16 + ln][dk*32 + hi*8], sacc1);

    // ---- online softmax, defer-max (THR=8) ----
    float vv0[4], vv1[4], mx[4];
    bool need = false;
    #pragma unroll
    for (int r = 0; r < 4; ++r) {
      const int qpos = qrow0 + hi*4 + r;
      const int kp0 = kb + ln, kp1 = kb + 16 + ln;
      const bool ok0 = (kp0 <= qpos) && (kp0 >= qpos - lo_off);
      const bool ok1 = (kp1 <= qpos) && (kp1 >= qpos - lo_off);
      vv0[r] = ok0 ? sacc0[r] * sm_scale : MASKED;
      vv1[r] = ok1 ? sacc1[r] * sm_scale : MASKED;
      float t = fmaxf(vv0[r], vv1[r]);
      #pragma unroll
      for (int off = 1; off < 16; off <<= 1)
        t = fmaxf(t, __shfl_xor(t, off));
      mx[r] = t;
      need = need || (t > m[r] + 8.0f);
    }
    if (__any(need)) {
      #pragma unroll
      for (int r = 0; r < 4; ++r) {
        const float mn   = fmaxf(m[r], mx[r]);
        const float corr = __expf(m[r] - mn);
        l[r] *= corr;
        m[r] = mn;
        #pragma unroll
        for (int nt = 0; nt < 8; ++nt) oacc[nt][r] *= corr;
      }
    }
    #pragma unroll
    for (int r = 0; r < 4; ++r) {
      const float p0 = __expf(vv0[r] - m[r]);
      const float p1 = __expf(vv1[r] - m[r]);
      float ps = p0 + p1;
      #pragma unroll
      for (int off = 1; off < 16; off <<= 1)
        ps += __shfl_xor(ps, off);
      l[r] += ps;
      Pl[wid][hi*4 + r][ln] = cvt_pk_bf16(p0, p1);
    }

    // ---- PV ----
    u16x8 pa;
    {
      const unsigned* pr = &Pl[wid][ln][(hi & 1) * 8];
      u32x4 wa = *(const u32x4*)pr;
      u32x4 wb = *(const u32x4*)(pr + 4);
      const unsigned sel = (hi < 2) ? 0x05040100u : 0x07060302u;
      u32x4 t = { __builtin_amdgcn_perm(wa[1], wa[0], sel),
                  __builtin_amdgcn_perm(wa[3], wa[2], sel),
                  __builtin_amdgcn_perm(wb[1], wb[0], sel),
                  __builtin_amdgcn_perm(wb[3], wb[2], sel) };
      pa = __builtin_bit_cast(u16x8, t);
    }
    #pragma unroll
    for (int nt = 0; nt < 8; ++nt) {
      const u16x8 vb = *(const u16x8*)&Vt[nt*16 + ln][hi*8];
      oacc[nt] = mfma_bf16(pa, vb, oacc[nt]);
    }
  }

  // ---- epilogue ----
  if (nch == 1) {
    const float sink = sinks[h];
    #pragma unroll
    for (int r = 0; r < 4; ++r) {
      const float M  = fmaxf(m[r], sink);
      const float ed = __expf(m[r] - M);
      const float fac = ed / (l[r] * ed + __expf(sink - M));
      const int qpos = qrow0 + hi*4 + r;
      float* op = out + ((size_t)(h * SLEN + qpos) * DDIM) + ln;
      #pragma unroll
      for (int nt = 0; nt < 8; ++nt) op[nt * 16] = oacc[nt][r] * fac;
    }
  } else {
    const size_t Lb = ((size_t)(h * 32 + qt)) * 2 + c;
    #pragma unroll
    for (int r = 0; r < 4; ++r) {
      const int lr = wid * 16 + hi * 4 + r;
      unsigned short* po = pO + (Lb * 64 + lr) * 128 + ln;
      #pragma unroll
      for (int nt = 0; nt < 8; ++nt) po[nt * 16] = f2bfu(oacc[nt][r]);
      if (ln == 0) { pm[Lb * 64 + lr] = m[r]; pl[Lb * 64 + lr] = l[r]; }
    }
  }
}

// ---- merge two chunk partials + sink ----
__global__ __launch_bounds__(256) void merge2(
    const unsigned short* __restrict__ pO, const float* __restrict__ pm,
    const float* __restrict__ pl, const float* __restrict__ sinks,
    float* __restrict__ out) {
  const int blk = blockIdx.x;        // h*32 + qt
  const int h   = blk >> 5;
  const int row = threadIdx.x >> 2;  // 0..63
  const int d0  = (threadIdx.x & 3) * 32;
  const size_t b0 = (size_t)blk * 2, b1 = b0 + 1;
  const float m0 = pm[b0 * 64 + row], l0 = pl[b0 * 64 + row];
  const float m1 = pm[b1 * 64 + row], l1 = pl[b1 * 64 + row];
  const float sink = sinks[h];
  const float M  = fmaxf(fmaxf(m0, m1), sink);
  const float e0 = __expf(m0 - M), e1 = __expf(m1 - M);
  const float inv = 1.0f / (l0 * e0 + l1 * e1 + __expf(sink - M));
  const float s0 = e0 * inv, s1 = e1 * inv;
  const unsigned short* p0 = pO + (b0 * 64 + row) * 128 + d0;
  const unsigned short* p1 = pO + (b1 * 64 + row) * 128 + d0;
  float* op = out + ((size_t)blk * 64 + row) * 128 + d0;
  #pragma unroll
  for (int i = 0; i < 4; ++i) {
    u16x8 a = *(const u16x8*)(p0 + i * 8);
    u16x8 b = *(const u16x8*)(p1 + i * 8);
    float4 o0, o1;
    o0.x = bfu2f(a[0]) * s0 + bfu2f(b[0]) * s1;
    o0.y = bfu2f(a[1]) * s0 + bfu2f(b[1]) * s1;
    o0.z = bfu2f(a[2]) * s0 + bfu2f(b[2]) * s1;
    o0.w = bfu2f(a[3]) * s0 + bfu2f(b[3]) * s1;
    o1.x = bfu2f(a[4]) * s0 + bfu2f(b[4]) * s1;
    o1.y = bfu2f(a[5]) * s0 + bfu2f(b[5]) * s1;
    o1.z = bfu2f(a[6]) * s0 + bfu2f(b[6]) * s1;
    o1.w = bfu2f(a[7]) * s0 + bfu2f(b[7]) * s1;
    *(float4*)(op + i * 8)     = o0;
    *(float4*)(op + i * 8 + 4) = o1;
  }
}

extern "C" void kernel_launch(void* const* d_in, const int* in_sizes, int n_in,
                              void* d_out, int out_size, void* d_ws, size_t ws_size,
                              hipStream_t stream) {
  const float* q     = (const float*)d_in[0];
  const float* k     = (const float*)d_in[1];
  const float* v     = (const float*)d_in[2];
  const float* sinks = (const float*)d_in[3];
  const int*   bw    = (const int*)d_in[4];
  float* out = (float*)d_out;

  const size_t kvBytes = (size_t)NKVH * SLEN * DDIM * 2;      // 8.39 MB each
  unsigned short* kbf = (unsigned short*)d_ws;
  unsigned short* vtg = kbf + (size_t)NKVH * SLEN * DDIM;

  const size_t nPart   = (size_t)2048 * 64;                   // rows of partials
  const size_t oBytes  = nPart * 128 * 2;                     // 33.6 MB bf16
  const size_t mlBytes = nPart * 4 * 2;                       // 1.0 MB
  const size_t need2   = 2 * kvBytes + oBytes + mlBytes;      // ~51.4 MB

  const int nch = (ws_size >= need2) ? 2 : 1;

  unsigned short* pO = vtg + (size_t)NKVH * SLEN * DDIM;
  float* pm = (float*)((char*)pO + oBytes);
  float* pl = pm + nPart;

  conv_k <<<dim3((NKVH*SLEN*DDIM) / (256*8)), 256, 0, stream>>>(k, (unsigned*)kbf);
  conv_vt<<<dim3(NKVH * 64 * 4),              256, 0, stream>>>(v, vtg);
  attn_fwd<<<dim3(1024 * nch), 256, 0, stream>>>(q, kbf, vtg, sinks, bw, out,
                                                 pO, pm, pl, nch);
  if (nch == 2)
    merge2<<<dim3(1024), 256, 0, stream>>>(pO, pm, pl, sinks, out);
}

// Round 7
// 79.766 us; speedup vs baseline: 1.5707x; 1.3969x over previous
//
#include <hip/hip_runtime.h>
#include <hip/hip_bf16.h>

typedef __bf16 bf16x8 __attribute__((ext_vector_type(8)));
typedef unsigned short u16x8 __attribute__((ext_vector_type(8)));
typedef unsigned int u32x4 __attribute__((ext_vector_type(4)));
typedef float f32x4 __attribute__((ext_vector_type(4)));

#define SLEN 2048
#define DDIM 128
#define NH   32
#define NKVH 8
#define QBLK 64
#define KVB  32
#define KPAD 136
#define VPAD 40
#define PW2  20    // u32 row width of P-exchange slab (80B: 16B-aligned, bank-spread)
#define MINIT  -1e30f
#define MASKED -3e30f

static __device__ __forceinline__ unsigned short f2bfu(float f) {
  union { float f; unsigned u; } x; x.f = f;
  return (unsigned short)((x.u + 0x7fffu + ((x.u >> 16) & 1u)) >> 16);
}
static __device__ __forceinline__ float bfu2f(unsigned short u) {
  union { unsigned u; float f; } x; x.u = ((unsigned)u) << 16;
  return x.f;
}
static __device__ __forceinline__ unsigned cvt_pk_bf16(float lo, float hi) {
  unsigned r;
  asm("v_cvt_pk_bf16_f32 %0, %1, %2" : "=v"(r) : "v"(lo), "v"(hi));
  return r;  // lo -> D[15:0], hi -> D[31:16]
}
static __device__ __forceinline__ f32x4 mfma_bf16(u16x8 a, u16x8 b, f32x4 c) {
  return __builtin_amdgcn_mfma_f32_16x16x32_bf16(
      __builtin_bit_cast(bf16x8, a), __builtin_bit_cast(bf16x8, b), c, 0, 0, 0);
}

// ---- fused prepass: K -> bf16 (blocks 0..1023), V -> bf16 transposed (1024..3071) ----
__global__ __launch_bounds__(256) void conv_kv(const float* __restrict__ k,
                                               const float* __restrict__ v,
                                               unsigned* __restrict__ kdst,
                                               unsigned short* __restrict__ vt) {
  __shared__ unsigned T32[32][17];
  const int bb = blockIdx.x;
  if (bb < 1024) {   // K: 1024 blocks x 256 thr x 8 elem = 2,097,152 = NKVH*SLEN*DDIM
    const int i = bb * 256 + threadIdx.x;
    const float4 f0 = ((const float4*)k)[2 * i];
    const float4 f1 = ((const float4*)k)[2 * i + 1];
    u32x4 o = { cvt_pk_bf16(f0.x, f0.y), cvt_pk_bf16(f0.z, f0.w),
                cvt_pk_bf16(f1.x, f1.y), cvt_pk_bf16(f1.z, f1.w) };
    ((u32x4*)kdst)[i] = o;
    return;
  }
  const int b   = bb - 1024;
  const int dt  = b & 3;
  const int st  = (b >> 2) & 63;
  const int kvh = b >> 8;
  const int r  = threadIdx.x >> 3;
  const int cg = threadIdx.x & 7;
  const float4 f = *(const float4*)(v + ((size_t)(kvh * SLEN + st * 32 + r) * DDIM) + dt * 32 + cg * 4);
  T32[r][cg * 2]     = cvt_pk_bf16(f.x, f.y);
  T32[r][cg * 2 + 1] = cvt_pk_bf16(f.z, f.w);
  __syncthreads();
  const int dr = threadIdx.x >> 3;
  const unsigned sel = (dr & 1) ? 0x07060302u : 0x05040100u;
  const unsigned a0 = T32[cg * 4 + 0][dr >> 1], a1 = T32[cg * 4 + 1][dr >> 1];
  const unsigned a2 = T32[cg * 4 + 2][dr >> 1], a3 = T32[cg * 4 + 3][dr >> 1];
  unsigned short* vp = vt + (size_t)kvh * DDIM * SLEN + (size_t)(dt * 32 + dr) * SLEN + st * 32 + cg * 4;
  const unsigned w0 = __builtin_amdgcn_perm(a1, a0, sel);
  const unsigned w1 = __builtin_amdgcn_perm(a3, a2, sel);
  vp[0] = (unsigned short)(w0 & 0xffff);
  vp[1] = (unsigned short)(w0 >> 16);
  vp[2] = (unsigned short)(w1 & 0xffff);
  vp[3] = (unsigned short)(w1 >> 16);
}

// ---- attention chunk kernel (swapped QK^T, in-register softmax) ----
__global__ __launch_bounds__(256, 4) void attn_fwd(
    const float* __restrict__ q, const unsigned short* __restrict__ kbf,
    const unsigned short* __restrict__ vtg, const float* __restrict__ sinks,
    const int* __restrict__ bwp, float* __restrict__ out,
    unsigned short* __restrict__ pO, float* __restrict__ pm,
    float* __restrict__ pl, const int nch) {
  __shared__ unsigned short Kl[KVB][KPAD];
  __shared__ unsigned short Vt[DDIM][VPAD];
  __shared__ unsigned Pex[4][16][PW2];   // P exchange: [wave][q][k-pair slot]
  __shared__ float SmS[4][16];           // per-wave row-stat broadcast

  const int tid  = threadIdx.x;
  const int wid  = tid >> 6;
  const int lane = tid & 63;
  const int ln   = lane & 15;
  const int hi   = lane >> 4;

  const int B   = blockIdx.x;
  const int x   = B & 7;
  const int j   = B >> 3;
  const int per = 4 * nch;
  const int qt  = 31 - (j / per);
  const int rem = j % per;
  const int hh  = (nch == 2) ? (rem >> 1) : rem;
  const int c   = (nch == 2) ? (rem & 1) : 0;
  const int h   = x * 4 + hh;
  const int kvh = x;
  const int q0  = qt * QBLK;
  const int qrow0 = q0 + wid * 16;
  const int qpos  = qrow0 + ln;          // this lane's q-row (softmax domain)

  const int bwv    = bwp[0];
  const int lo_off = (bwv > 0) ? (bwv - 1) : SLEN;

  const int T0 = max(0, q0 - lo_off) >> 5;
  const int T1 = (q0 + QBLK - 1) >> 5;
  const int N  = T1 - T0 + 1;
  const int ch = (N + nch - 1) / nch;
  const int Ts = T0 + c * ch;
  const int Te = min(T1, Ts + ch - 1);

  const float sm_scale = 0.08838834764831845f;

  // ---- Q fragments (serve as MFMA B-operand after the swap) ----
  u16x8 qf[4];
  {
    const float* qp = q + ((size_t)(h * SLEN + qpos) * DDIM) + hi * 8;
    #pragma unroll
    for (int dk = 0; dk < 4; ++dk) {
      float4 f0 = *(const float4*)(qp + dk * 32);
      float4 f1 = *(const float4*)(qp + dk * 32 + 4);
      u32x4 t = { cvt_pk_bf16(f0.x, f0.y), cvt_pk_bf16(f0.z, f0.w),
                  cvt_pk_bf16(f1.x, f1.y), cvt_pk_bf16(f1.z, f1.w) };
      qf[dk] = __builtin_bit_cast(u16x8, t);
    }
  }

  float m_ln = MINIT, l_ln = 0.0f;       // lane-local running stats for q = qpos
  f32x4 oacc[8];
  #pragma unroll
  for (int nt = 0; nt < 8; ++nt) oacc[nt] = f32x4{0.f, 0.f, 0.f, 0.f};

  const unsigned short* Kg = kbf + (size_t)kvh * SLEN * DDIM;
  const unsigned short* Vg = vtg + (size_t)kvh * DDIM * SLEN;

  const int kr0 = tid >> 4,          kc0 = (tid & 15) * 8;
  const int kr1 = (256 + tid) >> 4;
  const int vr0 = tid >> 2,          vc0 = (tid & 3) * 8;
  const int vr1 = (256 + tid) >> 2;

  const int kbS = Ts * 32, kbE = Te * 32;

  u16x8 pk0, pk1, pv0, pv1;
  {
    pk0 = *(const u16x8*)(Kg + (size_t)(kbS + kr0) * DDIM + kc0);
    pk1 = *(const u16x8*)(Kg + (size_t)(kbS + kr1) * DDIM + kc0);
    pv0 = *(const u16x8*)(Vg + (size_t)vr0 * SLEN + kbS + vc0);
    pv1 = *(const u16x8*)(Vg + (size_t)vr1 * SLEN + kbS + vc0);
  }

  for (int kb = kbS; kb <= kbE; kb += KVB) {
    __syncthreads();
    *(u16x8*)&Kl[kr0][kc0] = pk0;
    *(u16x8*)&Kl[kr1][kc0] = pk1;
    *(u16x8*)&Vt[vr0][vc0] = pv0;
    *(u16x8*)&Vt[vr1][vc0] = pv1;
    __syncthreads();

    {
      const int nb = min(kb + KVB, kbE);
      pk0 = *(const u16x8*)(Kg + (size_t)(nb + kr0) * DDIM + kc0);
      pk1 = *(const u16x8*)(Kg + (size_t)(nb + kr1) * DDIM + kc0);
      pv0 = *(const u16x8*)(Vg + (size_t)vr0 * SLEN + nb + vc0);
      pv1 = *(const u16x8*)(Vg + (size_t)vr1 * SLEN + nb + vc0);
    }

    if (kb > qrow0 + 15) continue;
    if (kb + KVB - 1 < qrow0 - lo_off) continue;

    // ---- QK^T (swapped): S^T = mfma(K_frag as A, Q_frag as B) ----
    f32x4 sacc0 = {0,0,0,0}, sacc1 = {0,0,0,0};
    #pragma unroll
    for (int dk = 0; dk < 4; ++dk)
      sacc0 = mfma_bf16(*(const u16x8*)&Kl[ln][dk*32 + hi*8], qf[dk], sacc0);
    #pragma unroll
    for (int dk = 0; dk < 4; ++dk)
      sacc1 = mfma_bf16(*(const u16x8*)&Kl[16 + ln][dk*32 + hi*8], qf[dk], sacc1);
    // lane holds S for q=qpos at k-local = hi*4+r (sacc0) and 16+hi*4+r (sacc1)

    // ---- mask + scale (all in registers, one q-row per lane) ----
    float p[8];
    #pragma unroll
    for (int r = 0; r < 4; ++r) {
      const int kp0 = kb + hi * 4 + r;
      const int kp1 = kp0 + 16;
      const bool ok0 = (kp0 <= qpos) && (kp0 >= qpos - lo_off);
      const bool ok1 = (kp1 <= qpos) && (kp1 >= qpos - lo_off);
      p[r]     = ok0 ? sacc0[r] * sm_scale : MASKED;
      p[4 + r] = ok1 ? sacc1[r] * sm_scale : MASKED;
    }

    // ---- row max: 7 in-register + 2 shfl ----
    float mx = fmaxf(fmaxf(fmaxf(p[0], p[1]), fmaxf(p[2], p[3])),
                     fmaxf(fmaxf(p[4], p[5]), fmaxf(p[6], p[7])));
    mx = fmaxf(mx, __shfl_xor(mx, 16));
    mx = fmaxf(mx, __shfl_xor(mx, 32));

    // ---- defer-max rescale (THR=8), corr redistributed via 16-float LDS row ----
    if (__any(mx > m_ln + 8.0f)) {
      const float mn   = fmaxf(m_ln, mx);
      const float corr = __expf(m_ln - mn);
      l_ln *= corr;
      m_ln = mn;
      if (hi == 0) SmS[wid][ln] = corr;
      float corr4[4];
      #pragma unroll
      for (int r = 0; r < 4; ++r) corr4[r] = SmS[wid][hi * 4 + r];
      #pragma unroll
      for (int nt = 0; nt < 8; ++nt)
        #pragma unroll
        for (int r = 0; r < 4; ++r) oacc[nt][r] *= corr4[r];
    }

    // ---- exp + row sum ----
    float s = 0.0f;
    #pragma unroll
    for (int jj = 0; jj < 8; ++jj) { p[jj] = __expf(p[jj] - m_ln); s += p[jj]; }
    s += __shfl_xor(s, 16);
    s += __shfl_xor(s, 32);
    l_ln += s;

    // ---- pack P (k-order pairs) and exchange to A-frag layout ----
    // slot s (u32) of row q covers k-pair {2s, 2s+1}
    Pex[wid][ln][hi * 2]         = cvt_pk_bf16(p[0], p[1]);   // k = hi*4+0,1
    Pex[wid][ln][hi * 2 + 1]     = cvt_pk_bf16(p[2], p[3]);   // k = hi*4+2,3
    Pex[wid][ln][8 + hi * 2]     = cvt_pk_bf16(p[4], p[5]);   // k = 16+hi*4+0,1
    Pex[wid][ln][8 + hi * 2 + 1] = cvt_pk_bf16(p[6], p[7]);   // k = 16+hi*4+2,3
    const u32x4 paw = *(const u32x4*)&Pex[wid][ln][hi * 4];   // k = hi*8 .. hi*8+7
    const u16x8 pa  = __builtin_bit_cast(u16x8, paw);

    // ---- PV: O += P[16x32] * V[32x128] ----
    #pragma unroll
    for (int nt = 0; nt < 8; ++nt) {
      const u16x8 vb = *(const u16x8*)&Vt[nt*16 + ln][hi*8];
      oacc[nt] = mfma_bf16(pa, vb, oacc[nt]);
    }
  }

  // ---- epilogue ----
  if (nch == 1) {
    const float sink = sinks[h];
    const float M  = fmaxf(m_ln, sink);
    const float ed = __expf(m_ln - M);
    const float fac_ln = ed / (l_ln * ed + __expf(sink - M));
    if (hi == 0) SmS[wid][ln] = fac_ln;
    float fac4[4];
    #pragma unroll
    for (int r = 0; r < 4; ++r) fac4[r] = SmS[wid][hi * 4 + r];
    #pragma unroll
    for (int r = 0; r < 4; ++r) {
      float* op = out + ((size_t)(h * SLEN + qrow0 + hi*4 + r) * DDIM) + ln;
      #pragma unroll
      for (int nt = 0; nt < 8; ++nt) op[nt * 16] = oacc[nt][r] * fac4[r];
    }
  } else {
    const size_t Lb = ((size_t)(h * 32 + qt)) * 2 + c;
    if (hi == 0) {
      pm[Lb * 64 + wid * 16 + ln] = m_ln;
      pl[Lb * 64 + wid * 16 + ln] = l_ln;
    }
    #pragma unroll
    for (int r = 0; r < 4; ++r) {
      unsigned short* po = pO + (Lb * 64 + wid * 16 + hi * 4 + r) * 128 + ln;
      #pragma unroll
      for (int nt = 0; nt < 8; ++nt) po[nt * 16] = f2bfu(oacc[nt][r]);
    }
  }
}

// ---- merge two chunk partials + sink ----
__global__ __launch_bounds__(256) void merge2(
    const unsigned short* __restrict__ pO, const float* __restrict__ pm,
    const float* __restrict__ pl, const float* __restrict__ sinks,
    float* __restrict__ out) {
  const int blk = blockIdx.x;        // h*32 + qt
  const int h   = blk >> 5;
  const int row = threadIdx.x >> 2;  // 0..63
  const int d0  = (threadIdx.x & 3) * 32;
  const size_t b0 = (size_t)blk * 2, b1 = b0 + 1;
  const float m0 = pm[b0 * 64 + row], l0 = pl[b0 * 64 + row];
  const float m1 = pm[b1 * 64 + row], l1 = pl[b1 * 64 + row];
  const float sink = sinks[h];
  const float M  = fmaxf(fmaxf(m0, m1), sink);
  const float e0 = __expf(m0 - M), e1 = __expf(m1 - M);
  const float inv = 1.0f / (l0 * e0 + l1 * e1 + __expf(sink - M));
  const float s0 = e0 * inv, s1 = e1 * inv;
  const unsigned short* p0 = pO + (b0 * 64 + row) * 128 + d0;
  const unsigned short* p1 = pO + (b1 * 64 + row) * 128 + d0;
  float* op = out + ((size_t)blk * 64 + row) * 128 + d0;
  #pragma unroll
  for (int i = 0; i < 4; ++i) {
    u16x8 a = *(const u16x8*)(p0 + i * 8);
    u16x8 b = *(const u16x8*)(p1 + i * 8);
    float4 o0, o1;
    o0.x = bfu2f(a[0]) * s0 + bfu2f(b[0]) * s1;
    o0.y = bfu2f(a[1]) * s0 + bfu2f(b[1]) * s1;
    o0.z = bfu2f(a[2]) * s0 + bfu2f(b[2]) * s1;
    o0.w = bfu2f(a[3]) * s0 + bfu2f(b[3]) * s1;
    o1.x = bfu2f(a[4]) * s0 + bfu2f(b[4]) * s1;
    o1.y = bfu2f(a[5]) * s0 + bfu2f(b[5]) * s1;
    o1.z = bfu2f(a[6]) * s0 + bfu2f(b[6]) * s1;
    o1.w = bfu2f(a[7]) * s0 + bfu2f(b[7]) * s1;
    *(float4*)(op + i * 8)     = o0;
    *(float4*)(op + i * 8 + 4) = o1;
  }
}

extern "C" void kernel_launch(void* const* d_in, const int* in_sizes, int n_in,
                              void* d_out, int out_size, void* d_ws, size_t ws_size,
                              hipStream_t stream) {
  const float* q     = (const float*)d_in[0];
  const float* k     = (const float*)d_in[1];
  const float* v     = (const float*)d_in[2];
  const float* sinks = (const float*)d_in[3];
  const int*   bw    = (const int*)d_in[4];
  float* out = (float*)d_out;

  const size_t kvBytes = (size_t)NKVH * SLEN * DDIM * 2;
  unsigned short* kbf = (unsigned short*)d_ws;
  unsigned short* vtg = kbf + (size_t)NKVH * SLEN * DDIM;

  const size_t nPart   = (size_t)2048 * 64;
  const size_t oBytes  = nPart * 128 * 2;
  const size_t mlBytes = nPart * 4 * 2;
  const size_t need2   = 2 * kvBytes + oBytes + mlBytes;

  const int nch = (ws_size >= need2) ? 2 : 1;

  unsigned short* pO = vtg + (size_t)NKVH * SLEN * DDIM;
  float* pm = (float*)((char*)pO + oBytes);
  float* pl = pm + nPart;

  conv_kv<<<dim3(1024 + NKVH * 64 * 4), 256, 0, stream>>>(k, v, (unsigned*)kbf, vtg);
  attn_fwd<<<dim3(1024 * nch), 256, 0, stream>>>(q, kbf, vtg, sinks, bw, out,
                                                 pO, pm, pl, nch);
  if (nch == 2)
    merge2<<<dim3(1024), 256, 0, stream>>>(pO, pm, pl, sinks, out);
}